// Round 2
// baseline (2800.093 us; speedup 1.0000x reference)
//
#include <hip/hip_runtime.h>
#include <hip/hip_bf16.h>

#define NNODES 20000
#define NEDGES 200000
#define NCD 32
#define FDIMD 13
#define FHIDD 64
#define NREPD 10
#define OUTCD (NCD * (NREPD + 1))   // 352
#define YROW 2080                   // 64*32 filter cols + 32 bias cols

static __device__ __forceinline__ float bf2f(unsigned short u) {
    union { unsigned u; float f; } cv; cv.u = ((unsigned)u) << 16; return cv.f;
}

// ---------------------------------------------------------------------------
__global__ __launch_bounds__(256) void k_copy_h0(const float* __restrict__ hx,
                                                 float* __restrict__ out) {
    int tid = blockIdx.x * 256 + threadIdx.x;
    if (tid < NNODES * NCD)
        out[(size_t)(tid >> 5) * OUTCD + (tid & 31)] = hx[tid];
}

// in-degree (float, for mean-norm) and out-degree (int, for CSR)
__global__ __launch_bounds__(256) void k_degrees(const int* __restrict__ ei,
                                                 float* __restrict__ indeg,
                                                 int* __restrict__ outcnt) {
    int e = blockIdx.x * 256 + threadIdx.x;
    if (e < NEDGES) {
        atomicAdd(&indeg[ei[NEDGES + e]], 1.0f);
        atomicAdd(&outcnt[ei[e]], 1);
    }
}

// exclusive scan of outcnt -> csr_off (single block)
__global__ __launch_bounds__(256) void k_scan(const int* __restrict__ outcnt,
                                              int* __restrict__ csr_off) {
    __shared__ int s_w[4];
    __shared__ int s_base;
    int t = threadIdx.x;
    if (t == 0) s_base = 0;
    __syncthreads();
    for (int base = 0; base < NNODES; base += 256) {
        int i = base + t;
        int v = (i < NNODES) ? outcnt[i] : 0;
        int x = v;
        #pragma unroll
        for (int d = 1; d < 64; d <<= 1) {
            int y = __shfl_up(x, d);
            if ((t & 63) >= d) x += y;
        }
        if ((t & 63) == 63) s_w[t >> 6] = x;
        __syncthreads();
        int wid = t >> 6, wb = 0;
        for (int w = 0; w < wid; ++w) wb += s_w[w];
        if (i < NNODES) csr_off[i] = s_base + wb + x - v;
        int ctot = s_w[0] + s_w[1] + s_w[2] + s_w[3];
        __syncthreads();
        if (t == 0) s_base += ctot;
        __syncthreads();
    }
    if (t == 0) csr_off[NNODES] = s_base;
}

__global__ __launch_bounds__(256) void k_fill(const int* __restrict__ ei,
                                              const int* __restrict__ csr_off,
                                              int* __restrict__ cursor,
                                              int* __restrict__ csr_e) {
    int e = blockIdx.x * 256 + threadIdx.x;
    if (e < NEDGES) {
        int s = ei[e];
        int p = atomicAdd(&cursor[s], 1);
        csr_e[csr_off[s] + p] = e;
    }
}

// ---------------------------------------------------------------------------
// h1[e,k] = relu(ef[e] @ fW1 + fb1)[k], bf16. Block = 4 edges x 64 cols.
__global__ __launch_bounds__(256) void k_h1(const float* __restrict__ ef,
                                            const float* __restrict__ fW1,
                                            const float* __restrict__ fb1,
                                            __hip_bfloat16* __restrict__ h1b) {
    __shared__ float s_w1[FDIMD * FHIDD];
    __shared__ float s_ef[4 * FDIMD];
    int t = threadIdx.x;
    for (int idx = t; idx < FDIMD * FHIDD; idx += 256) s_w1[idx] = fW1[idx];
    if (t < 4 * FDIMD) s_ef[t] = ef[(size_t)blockIdx.x * 4 * FDIMD + t];
    __syncthreads();
    int je = t >> 6, k = t & 63;
    float v = fb1[k];
    #pragma unroll
    for (int j = 0; j < FDIMD; ++j) v += s_ef[je * FDIMD + j] * s_w1[j * FHIDD + k];
    h1b[(size_t)(blockIdx.x * 4 + je) * FHIDD + k] = __float2bfloat16(fmaxf(v, 0.f));
}

// ---------------------------------------------------------------------------
// Y[n, k*32+o] = sum_i hx[n,i] * fW2[k, i*32+o]; Y[n, 2048+o] = sum_i hx[n,i]*fb2[i*32+o]
// Tile: 32 nodes x 256 cols per block.
__global__ __launch_bounds__(256) void k_ygemm(const float* __restrict__ out, int r,
                                               int n0, int cn,
                                               const float* __restrict__ fW2,
                                               const float* __restrict__ fb2,
                                               __hip_bfloat16* __restrict__ Yb) {
    __shared__ float s_x[32][32];
    __shared__ float s_w[32][256];
    int t = threadIdx.x;
    int bn = blockIdx.x * 32;
    int j0 = blockIdx.y * 256;
    for (int idx = t; idx < 1024; idx += 256) {
        int nl = idx >> 5, i = idx & 31;
        s_x[nl][i] = (bn + nl < cn) ? out[(size_t)(n0 + bn + nl) * OUTCD + r * NCD + i] : 0.f;
    }
    for (int idx = t; idx < 32 * 256; idx += 256) {
        int i = idx >> 8, c = idx & 255;
        int j = j0 + c;
        float v = 0.f;
        if (j < 2048)       v = fW2[(size_t)(j >> 5) * 1024 + i * 32 + (j & 31)];
        else if (j < YROW)  v = fb2[i * 32 + (j - 2048)];
        s_w[i][c] = v;
    }
    __syncthreads();
    float wr[32];
    #pragma unroll
    for (int i = 0; i < 32; ++i) wr[i] = s_w[i][t];
    float acc[32];
    #pragma unroll
    for (int n = 0; n < 32; ++n) acc[n] = 0.f;
    #pragma unroll
    for (int n = 0; n < 32; ++n) {
        #pragma unroll
        for (int i4 = 0; i4 < 8; ++i4) {
            const float4 xv = *reinterpret_cast<const float4*>(&s_x[n][i4 * 4]);
            acc[n] += xv.x * wr[i4 * 4] + xv.y * wr[i4 * 4 + 1] +
                      xv.z * wr[i4 * 4 + 2] + xv.w * wr[i4 * 4 + 3];
        }
    }
    int j = j0 + t;
    if (j < YROW) {
        for (int n = 0; n < 32 && bn + n < cn; ++n)
            Yb[(size_t)(bn + n) * YROW + j] = __float2bfloat16(acc[n]);
    }
}

// ---------------------------------------------------------------------------
// One block per src node: Y row -> LDS, loop out-edges in batches of 4,
// msg[e,o] = B[o] + sum_k h1[e,k]*Y[k*32+o], scatter-add to agg[dst].
__global__ __launch_bounds__(256) void k_edge(const int* __restrict__ ei,
                                              const int* __restrict__ csr_off,
                                              const int* __restrict__ csr_e,
                                              const __hip_bfloat16* __restrict__ h1b,
                                              const __hip_bfloat16* __restrict__ Yb,
                                              int n0, float* __restrict__ agg) {
    __shared__ float s_Y[YROW];
    __shared__ float s_h1[4][64];
    __shared__ int s_dst[4];
    int t = threadIdx.x;
    int n = n0 + blockIdx.x;
    const uint4* yrow = reinterpret_cast<const uint4*>(Yb + (size_t)blockIdx.x * YROW);
    for (int idx = t; idx < YROW / 8; idx += 256) {
        uint4 q = yrow[idx];
        unsigned u[4] = {q.x, q.y, q.z, q.w};
        #pragma unroll
        for (int w = 0; w < 4; ++w) {
            s_Y[idx * 8 + w * 2]     = bf2f((unsigned short)(u[w] & 0xffff));
            s_Y[idx * 8 + w * 2 + 1] = bf2f((unsigned short)(u[w] >> 16));
        }
    }
    int start = csr_off[n];
    int cnt   = csr_off[n + 1] - start;
    for (int base = 0; base < cnt; base += 4) {
        int nb = min(4, cnt - base);
        __syncthreads();
        if (t < nb * 64) {
            int je = t >> 6, k = t & 63;
            int e = csr_e[start + base + je];
            s_h1[je][k] = __bfloat162float(h1b[(size_t)e * FHIDD + k]);
        }
        if (t < nb) s_dst[t] = ei[NEDGES + csr_e[start + base + t]];
        __syncthreads();
        int je = t >> 6;
        if (je < nb) {
            int o = t & 31, ih = (t >> 5) & 1;
            float acc = 0.f;
            #pragma unroll
            for (int kk = 0; kk < 32; ++kk) {
                int k = kk * 2 + ih;
                acc += s_h1[je][k] * s_Y[k * 32 + o];
            }
            acc += __shfl_down(acc, 32);
            if (ih == 0)
                atomicAdd(&agg[(size_t)s_dst[je] * NCD + o], acc + s_Y[2048 + o]);
        }
    }
}

// ---------------------------------------------------------------------------
__global__ __launch_bounds__(256) void k_gru(
    const float* __restrict__ agg, const float* __restrict__ indeg,
    const float* __restrict__ Wi, const float* __restrict__ Wh,
    const float* __restrict__ bi, const float* __restrict__ bh,
    float* __restrict__ out, int r) {
    __shared__ float sWiT[96 * 36];
    __shared__ float sWhT[96 * 36];
    __shared__ float s_x[8][32];
    __shared__ float s_h[8][32];
    const int t = threadIdx.x;
    for (int idx = t; idx < 96 * 32; idx += 256) {
        const int g = idx >> 5, i = idx & 31;
        sWiT[g * 36 + i] = Wi[i * 96 + g];
        sWhT[g * 36 + i] = Wh[i * 96 + g];
    }
    const int tid = blockIdx.x * 256 + t;
    const int n   = tid >> 5;
    const int c   = t & 31;
    const int ln  = t >> 5;
    {
        const float invd = 1.0f / fmaxf(indeg[n], 1.0f);
        s_x[ln][c] = agg[(size_t)n * NCD + c] * invd;
        s_h[ln][c] = out[(size_t)n * OUTCD + r * NCD + c];
    }
    __syncthreads();
    float ir = bi[c], iz = bi[NCD + c], in_ = bi[2 * NCD + c];
    float hr = bh[c], hz = bh[NCD + c], hn = bh[2 * NCD + c];
    const float* wi_r = &sWiT[c * 36];
    const float* wi_z = &sWiT[(NCD + c) * 36];
    const float* wi_n = &sWiT[(2 * NCD + c) * 36];
    const float* wh_r = &sWhT[c * 36];
    const float* wh_z = &sWhT[(NCD + c) * 36];
    const float* wh_n = &sWhT[(2 * NCD + c) * 36];
    #pragma unroll
    for (int i4 = 0; i4 < 8; ++i4) {
        const float4 xx = *reinterpret_cast<const float4*>(&s_x[ln][i4 * 4]);
        const float4 hh = *reinterpret_cast<const float4*>(&s_h[ln][i4 * 4]);
        const float4 a = *reinterpret_cast<const float4*>(&wi_r[i4 * 4]);
        const float4 b = *reinterpret_cast<const float4*>(&wi_z[i4 * 4]);
        const float4 g = *reinterpret_cast<const float4*>(&wi_n[i4 * 4]);
        const float4 d = *reinterpret_cast<const float4*>(&wh_r[i4 * 4]);
        const float4 e = *reinterpret_cast<const float4*>(&wh_z[i4 * 4]);
        const float4 f = *reinterpret_cast<const float4*>(&wh_n[i4 * 4]);
        ir  += xx.x * a.x + xx.y * a.y + xx.z * a.z + xx.w * a.w;
        iz  += xx.x * b.x + xx.y * b.y + xx.z * b.z + xx.w * b.w;
        in_ += xx.x * g.x + xx.y * g.y + xx.z * g.z + xx.w * g.w;
        hr  += hh.x * d.x + hh.y * d.y + hh.z * d.z + hh.w * d.w;
        hz  += hh.x * e.x + hh.y * e.y + hh.z * e.z + hh.w * e.w;
        hn  += hh.x * f.x + hh.y * f.y + hh.z * f.z + hh.w * f.w;
    }
    const float rg = 1.f / (1.f + expf(-(ir + hr)));
    const float zg = 1.f / (1.f + expf(-(iz + hz)));
    const float ng = tanhf(in_ + rg * hn);
    out[(size_t)n * OUTCD + (r + 1) * NCD + c] = (1.f - zg) * ng + zg * s_h[ln][c];
}

// ---------------------------------------------------------------------------
extern "C" void kernel_launch(void* const* d_in, const int* in_sizes, int n_in,
                              void* d_out, int out_size, void* d_ws, size_t ws_size,
                              hipStream_t stream) {
    const float* hx  = (const float*)d_in[0];
    const int*   ei  = (const int*)d_in[1];
    const float* ef  = (const float*)d_in[2];
    const float* fW1 = (const float*)d_in[3];
    const float* fb1 = (const float*)d_in[4];
    const float* fW2 = (const float*)d_in[5];
    const float* fb2 = (const float*)d_in[6];
    const float* Wi  = (const float*)d_in[7];
    const float* Wh  = (const float*)d_in[8];
    const float* bi  = (const float*)d_in[9];
    const float* bh  = (const float*)d_in[10];
    float* out = (float*)d_out;

    char* ws = (char*)d_ws;
    size_t off = 0;
    auto take = [&](size_t bytes) -> void* {
        void* p = ws + off;
        off = (off + bytes + 255) & ~(size_t)255;
        return p;
    };
    __hip_bfloat16* h1b = (__hip_bfloat16*)take((size_t)NEDGES * FHIDD * 2);  // 25.6 MB
    float* agg    = (float*)take((size_t)NNODES * NCD * 4);                   // 2.56 MB
    float* indeg  = (float*)take((size_t)NNODES * 4);
    int*   outcnt = (int*)take((size_t)NNODES * 4);
    int*   csr_off= (int*)take((size_t)(NNODES + 1) * 4);
    int*   csr_e  = (int*)take((size_t)NEDGES * 4);
    int*   cursor = (int*)take((size_t)NNODES * 4);
    __hip_bfloat16* Yb = (__hip_bfloat16*)(ws + off);

    size_t avail = (ws_size > off) ? ws_size - off : 0;
    long long max_nodes = (long long)(avail / ((size_t)YROW * 2));
    if (max_nodes < 1) max_nodes = 1;
    if (max_nodes > NNODES) max_nodes = NNODES;
    int nchunk = (int)((NNODES + max_nodes - 1) / max_nodes);
    int cs = (NNODES + nchunk - 1) / nchunk;

    hipMemsetAsync(indeg,  0, (size_t)NNODES * 4, stream);
    hipMemsetAsync(outcnt, 0, (size_t)NNODES * 4, stream);
    hipMemsetAsync(cursor, 0, (size_t)NNODES * 4, stream);
    k_copy_h0<<<(NNODES * NCD) / 256, 256, 0, stream>>>(hx, out);
    k_degrees<<<(NEDGES + 255) / 256, 256, 0, stream>>>(ei, indeg, outcnt);
    k_scan<<<1, 256, 0, stream>>>(outcnt, csr_off);
    k_fill<<<(NEDGES + 255) / 256, 256, 0, stream>>>(ei, csr_off, cursor, csr_e);
    k_h1<<<NEDGES / 4, 256, 0, stream>>>(ef, fW1, fb1, h1b);

    for (int r = 0; r < NREPD; ++r) {
        hipMemsetAsync(agg, 0, (size_t)NNODES * NCD * 4, stream);
        for (int c = 0; c < nchunk; ++c) {
            int n0 = c * cs;
            int cn = (NNODES - n0 < cs) ? (NNODES - n0) : cs;
            if (cn <= 0) break;
            dim3 g((cn + 31) / 32, 9);
            k_ygemm<<<g, 256, 0, stream>>>(out, r, n0, cn, fW2, fb2, Yb);
            k_edge<<<cn, 256, 0, stream>>>(ei, csr_off, csr_e, h1b, Yb, n0, agg);
        }
        k_gru<<<(NNODES * NCD) / 256, 256, 0, stream>>>(agg, indeg, Wi, Wh, bi, bh, out, r);
    }
}

// Round 3
// 1683.679 us; speedup vs baseline: 1.6631x; 1.6631x over previous
//
#include <hip/hip_runtime.h>
#include <hip/hip_bf16.h>

#define NNODES 20000
#define NEDGES 200000
#define NCD 32
#define FDIMD 13
#define FHIDD 64
#define NREPD 10
#define OUTCD (NCD * (NREPD + 1))   // 352
#define YROW 2080                   // 64*32 filter cols + 32 bias cols
#define NCT 130                     // YROW/16 col tiles

typedef short bf16x8 __attribute__((ext_vector_type(8)));
typedef float f32x4 __attribute__((ext_vector_type(4)));

static __device__ __forceinline__ float bf2f(unsigned short u) {
    union { unsigned u; float f; } cv; cv.u = ((unsigned)u) << 16; return cv.f;
}

// ---------------------------------------------------------------------------
__global__ __launch_bounds__(256) void k_copy_h0(const float* __restrict__ hx,
                                                 float* __restrict__ out,
                                                 __hip_bfloat16* __restrict__ hxb) {
    int tid = blockIdx.x * 256 + threadIdx.x;
    if (tid < NNODES * NCD) {
        float v = hx[tid];
        out[(size_t)(tid >> 5) * OUTCD + (tid & 31)] = v;
        hxb[tid] = __float2bfloat16(v);
    }
}

__global__ __launch_bounds__(256) void k_degrees(const int* __restrict__ ei,
                                                 float* __restrict__ indeg,
                                                 int* __restrict__ outcnt) {
    int e = blockIdx.x * 256 + threadIdx.x;
    if (e < NEDGES) {
        atomicAdd(&indeg[ei[NEDGES + e]], 1.0f);
        atomicAdd(&outcnt[ei[e]], 1);
    }
}

__global__ __launch_bounds__(256) void k_scan(const int* __restrict__ outcnt,
                                              int* __restrict__ csr_off) {
    __shared__ int s_w[4];
    __shared__ int s_base;
    int t = threadIdx.x;
    if (t == 0) s_base = 0;
    __syncthreads();
    for (int base = 0; base < NNODES; base += 256) {
        int i = base + t;
        int v = (i < NNODES) ? outcnt[i] : 0;
        int x = v;
        #pragma unroll
        for (int d = 1; d < 64; d <<= 1) {
            int y = __shfl_up(x, d);
            if ((t & 63) >= d) x += y;
        }
        if ((t & 63) == 63) s_w[t >> 6] = x;
        __syncthreads();
        int wid = t >> 6, wb = 0;
        for (int w = 0; w < wid; ++w) wb += s_w[w];
        if (i < NNODES) csr_off[i] = s_base + wb + x - v;
        int ctot = s_w[0] + s_w[1] + s_w[2] + s_w[3];
        __syncthreads();
        if (t == 0) s_base += ctot;
        __syncthreads();
    }
    if (t == 0) csr_off[NNODES] = s_base;
}

__global__ __launch_bounds__(256) void k_fill(const int* __restrict__ ei,
                                              const int* __restrict__ csr_off,
                                              int* __restrict__ cursor,
                                              int* __restrict__ csr_e) {
    int e = blockIdx.x * 256 + threadIdx.x;
    if (e < NEDGES) {
        int s = ei[e];
        int p = atomicAdd(&cursor[s], 1);
        csr_e[csr_off[s] + p] = e;
    }
}

// ---------------------------------------------------------------------------
// h1[e,k] = relu(ef[e] @ fW1 + fb1)[k], bf16. Block = 4 edges x 64 cols.
__global__ __launch_bounds__(256) void k_h1(const float* __restrict__ ef,
                                            const float* __restrict__ fW1,
                                            const float* __restrict__ fb1,
                                            __hip_bfloat16* __restrict__ h1b) {
    __shared__ float s_w1[FDIMD * FHIDD];
    __shared__ float s_ef[4 * FDIMD];
    int t = threadIdx.x;
    for (int idx = t; idx < FDIMD * FHIDD; idx += 256) s_w1[idx] = fW1[idx];
    if (t < 4 * FDIMD) s_ef[t] = ef[(size_t)blockIdx.x * 4 * FDIMD + t];
    __syncthreads();
    int je = t >> 6, k = t & 63;
    float v = fb1[k];
    #pragma unroll
    for (int j = 0; j < FDIMD; ++j) v += s_ef[je * FDIMD + j] * s_w1[j * FHIDD + k];
    h1b[(size_t)(blockIdx.x * 4 + je) * FHIDD + k] = __float2bfloat16(fmaxf(v, 0.f));
}

// ---------------------------------------------------------------------------
// Precompute lane-swizzled B-fragments of W2r (rearranged fW2 + fb2 bias cols).
// W2r[i, j]: j<2048 -> fW2[j>>5, i*32 + (j&31)]; j>=2048 -> fb2[i*32 + (j-2048)].
// Fragment: W2f[ct*1024 + lane*8 + jj] = W2r[(lane>>4)*8+jj][ct*16 + (lane&15)]
__global__ __launch_bounds__(256) void k_w2frag(const float* __restrict__ fW2,
                                                const float* __restrict__ fb2,
                                                __hip_bfloat16* __restrict__ W2f) {
    int idx = blockIdx.x * 256 + threadIdx.x;
    if (idx >= NCT * 64) return;
    int ct = idx >> 6, lane = idx & 63;
    int j = ct * 16 + (lane & 15);
    __align__(16) __hip_bfloat16 tmp[8];
    #pragma unroll
    for (int jj = 0; jj < 8; ++jj) {
        int i = (lane >> 4) * 8 + jj;
        float v = (j < 2048) ? fW2[(size_t)(j >> 5) * 1024 + i * 32 + (j & 31)]
                             : fb2[i * 32 + (j - 2048)];
        tmp[jj] = __float2bfloat16(v);
    }
    *reinterpret_cast<uint4*>(&W2f[(size_t)ct * 1024 + lane * 8]) =
        *reinterpret_cast<const uint4*>(tmp);
}

// ---------------------------------------------------------------------------
// Y[n, :] = hxb[n, :] @ W2r via one mfma_f32_16x16x32_bf16 per 16x16 tile.
// Block = 4 waves = same 16-node tile, 4 consecutive col tiles.
__global__ __launch_bounds__(256) void k_ygemm2(const __hip_bfloat16* __restrict__ hxb,
                                                const __hip_bfloat16* __restrict__ W2f,
                                                int n0,
                                                __hip_bfloat16* __restrict__ Yb) {
    const int wave = threadIdx.x >> 6, lane = threadIdx.x & 63;
    const int ct = blockIdx.y * 4 + wave;
    if (ct >= NCT) return;
    const int nrel = blockIdx.x * 16;
    bf16x8 a = *reinterpret_cast<const bf16x8*>(
        hxb + (size_t)(n0 + nrel + (lane & 15)) * NCD + (lane >> 4) * 8);
    bf16x8 b = *reinterpret_cast<const bf16x8*>(W2f + (size_t)ct * 1024 + lane * 8);
    f32x4 c = {0.f, 0.f, 0.f, 0.f};
    c = __builtin_amdgcn_mfma_f32_16x16x32_bf16(a, b, c, 0, 0, 0);
    const int col = ct * 16 + (lane & 15);
    size_t rb = (size_t)(nrel + (lane >> 4) * 4) * YROW + col;
    #pragma unroll
    for (int r = 0; r < 4; ++r)
        Yb[rb + (size_t)r * YROW] = __float2bfloat16(c[r]);
}

// ---------------------------------------------------------------------------
// One block per src node: Y row -> LDS, loop out-edges in batches of 4,
// msg[e,o] = B[o] + sum_k h1[e,k]*Y[k*32+o], scatter-add to agg[dst].
__global__ __launch_bounds__(256) void k_edge(const int* __restrict__ ei,
                                              const int* __restrict__ csr_off,
                                              const int* __restrict__ csr_e,
                                              const __hip_bfloat16* __restrict__ h1b,
                                              const __hip_bfloat16* __restrict__ Yb,
                                              int n0, float* __restrict__ agg) {
    __shared__ float s_Y[YROW];
    __shared__ float s_h1[4][64];
    __shared__ int s_dst[4];
    int t = threadIdx.x;
    int n = n0 + blockIdx.x;
    const uint4* yrow = reinterpret_cast<const uint4*>(Yb + (size_t)blockIdx.x * YROW);
    for (int idx = t; idx < YROW / 8; idx += 256) {
        uint4 q = yrow[idx];
        unsigned u[4] = {q.x, q.y, q.z, q.w};
        #pragma unroll
        for (int w = 0; w < 4; ++w) {
            s_Y[idx * 8 + w * 2]     = bf2f((unsigned short)(u[w] & 0xffff));
            s_Y[idx * 8 + w * 2 + 1] = bf2f((unsigned short)(u[w] >> 16));
        }
    }
    int start = csr_off[n];
    int cnt   = csr_off[n + 1] - start;
    for (int base = 0; base < cnt; base += 4) {
        int nb = min(4, cnt - base);
        __syncthreads();
        if (t < nb * 64) {
            int je = t >> 6, k = t & 63;
            int e = csr_e[start + base + je];
            s_h1[je][k] = __bfloat162float(h1b[(size_t)e * FHIDD + k]);
        }
        if (t < nb) s_dst[t] = ei[NEDGES + csr_e[start + base + t]];
        __syncthreads();
        int je = t >> 6;
        if (je < nb) {
            int o = t & 31, ih = (t >> 5) & 1;
            float acc = 0.f;
            #pragma unroll
            for (int kk = 0; kk < 32; ++kk) {
                int k = kk * 2 + ih;
                acc += s_h1[je][k] * s_Y[k * 32 + o];
            }
            acc += __shfl_down(acc, 32);
            if (ih == 0)
                atomicAdd(&agg[(size_t)s_dst[je] * NCD + o], acc + s_Y[2048 + o]);
        }
    }
}

// ---------------------------------------------------------------------------
__global__ __launch_bounds__(256) void k_gru(
    const float* __restrict__ agg, const float* __restrict__ indeg,
    const float* __restrict__ Wi, const float* __restrict__ Wh,
    const float* __restrict__ bi, const float* __restrict__ bh,
    float* __restrict__ out, __hip_bfloat16* __restrict__ hxb, int r) {
    __shared__ float sWiT[96 * 36];
    __shared__ float sWhT[96 * 36];
    __shared__ float s_x[8][32];
    __shared__ float s_h[8][32];
    const int t = threadIdx.x;
    for (int idx = t; idx < 96 * 32; idx += 256) {
        const int g = idx >> 5, i = idx & 31;
        sWiT[g * 36 + i] = Wi[i * 96 + g];
        sWhT[g * 36 + i] = Wh[i * 96 + g];
    }
    const int tid = blockIdx.x * 256 + t;
    const int n   = tid >> 5;
    const int c   = t & 31;
    const int ln  = t >> 5;
    {
        const float invd = 1.0f / fmaxf(indeg[n], 1.0f);
        s_x[ln][c] = agg[(size_t)n * NCD + c] * invd;
        s_h[ln][c] = out[(size_t)n * OUTCD + r * NCD + c];
    }
    __syncthreads();
    float ir = bi[c], iz = bi[NCD + c], in_ = bi[2 * NCD + c];
    float hr = bh[c], hz = bh[NCD + c], hn = bh[2 * NCD + c];
    const float* wi_r = &sWiT[c * 36];
    const float* wi_z = &sWiT[(NCD + c) * 36];
    const float* wi_n = &sWiT[(2 * NCD + c) * 36];
    const float* wh_r = &sWhT[c * 36];
    const float* wh_z = &sWhT[(NCD + c) * 36];
    const float* wh_n = &sWhT[(2 * NCD + c) * 36];
    #pragma unroll
    for (int i4 = 0; i4 < 8; ++i4) {
        const float4 xx = *reinterpret_cast<const float4*>(&s_x[ln][i4 * 4]);
        const float4 hh = *reinterpret_cast<const float4*>(&s_h[ln][i4 * 4]);
        const float4 a = *reinterpret_cast<const float4*>(&wi_r[i4 * 4]);
        const float4 b = *reinterpret_cast<const float4*>(&wi_z[i4 * 4]);
        const float4 g = *reinterpret_cast<const float4*>(&wi_n[i4 * 4]);
        const float4 d = *reinterpret_cast<const float4*>(&wh_r[i4 * 4]);
        const float4 e = *reinterpret_cast<const float4*>(&wh_z[i4 * 4]);
        const float4 f = *reinterpret_cast<const float4*>(&wh_n[i4 * 4]);
        ir  += xx.x * a.x + xx.y * a.y + xx.z * a.z + xx.w * a.w;
        iz  += xx.x * b.x + xx.y * b.y + xx.z * b.z + xx.w * b.w;
        in_ += xx.x * g.x + xx.y * g.y + xx.z * g.z + xx.w * g.w;
        hr  += hh.x * d.x + hh.y * d.y + hh.z * d.z + hh.w * d.w;
        hz  += hh.x * e.x + hh.y * e.y + hh.z * e.z + hh.w * e.w;
        hn  += hh.x * f.x + hh.y * f.y + hh.z * f.z + hh.w * f.w;
    }
    const float rg = 1.f / (1.f + expf(-(ir + hr)));
    const float zg = 1.f / (1.f + expf(-(iz + hz)));
    const float ng = tanhf(in_ + rg * hn);
    const float hv = (1.f - zg) * ng + zg * s_h[ln][c];
    out[(size_t)n * OUTCD + (r + 1) * NCD + c] = hv;
    hxb[(size_t)n * NCD + c] = __float2bfloat16(hv);
}

// ---------------------------------------------------------------------------
extern "C" void kernel_launch(void* const* d_in, const int* in_sizes, int n_in,
                              void* d_out, int out_size, void* d_ws, size_t ws_size,
                              hipStream_t stream) {
    const float* hx  = (const float*)d_in[0];
    const int*   ei  = (const int*)d_in[1];
    const float* ef  = (const float*)d_in[2];
    const float* fW1 = (const float*)d_in[3];
    const float* fb1 = (const float*)d_in[4];
    const float* fW2 = (const float*)d_in[5];
    const float* fb2 = (const float*)d_in[6];
    const float* Wi  = (const float*)d_in[7];
    const float* Wh  = (const float*)d_in[8];
    const float* bi  = (const float*)d_in[9];
    const float* bh  = (const float*)d_in[10];
    float* out = (float*)d_out;

    char* ws = (char*)d_ws;
    size_t off = 0;
    auto take = [&](size_t bytes) -> void* {
        void* p = ws + off;
        off = (off + bytes + 255) & ~(size_t)255;
        return p;
    };
    __hip_bfloat16* h1b = (__hip_bfloat16*)take((size_t)NEDGES * FHIDD * 2);  // 25.6 MB
    __hip_bfloat16* hxb = (__hip_bfloat16*)take((size_t)NNODES * NCD * 2);    // 1.28 MB
    __hip_bfloat16* W2f = (__hip_bfloat16*)take((size_t)NCT * 1024 * 2);      // 266 KB
    float* agg    = (float*)take((size_t)NNODES * NCD * 4);                   // 2.56 MB
    float* indeg  = (float*)take((size_t)NNODES * 4);
    int*   outcnt = (int*)take((size_t)NNODES * 4);
    int*   csr_off= (int*)take((size_t)(NNODES + 1) * 4);
    int*   csr_e  = (int*)take((size_t)NEDGES * 4);
    int*   cursor = (int*)take((size_t)NNODES * 4);
    __hip_bfloat16* Yb = (__hip_bfloat16*)(ws + off);

    size_t avail = (ws_size > off) ? ws_size - off : 0;
    long long max_nodes = (long long)(avail / ((size_t)YROW * 2));
    if (max_nodes < 16) max_nodes = 16;
    if (max_nodes > NNODES) max_nodes = NNODES;
    int nchunk = (int)((NNODES + max_nodes - 1) / max_nodes);
    int cs = (NNODES + nchunk - 1) / nchunk;
    cs = ((cs + 15) / 16) * 16;   // node tiles of 16 for MFMA

    hipMemsetAsync(indeg,  0, (size_t)NNODES * 4, stream);
    hipMemsetAsync(outcnt, 0, (size_t)NNODES * 4, stream);
    hipMemsetAsync(cursor, 0, (size_t)NNODES * 4, stream);
    k_copy_h0<<<(NNODES * NCD) / 256, 256, 0, stream>>>(hx, out, hxb);
    k_degrees<<<(NEDGES + 255) / 256, 256, 0, stream>>>(ei, indeg, outcnt);
    k_scan<<<1, 256, 0, stream>>>(outcnt, csr_off);
    k_fill<<<(NEDGES + 255) / 256, 256, 0, stream>>>(ei, csr_off, cursor, csr_e);
    k_h1<<<NEDGES / 4, 256, 0, stream>>>(ef, fW1, fb1, h1b);
    k_w2frag<<<(NCT * 64 + 255) / 256, 256, 0, stream>>>(fW2, fb2, W2f);

    for (int r = 0; r < NREPD; ++r) {
        hipMemsetAsync(agg, 0, (size_t)NNODES * NCD * 4, stream);
        for (int c = 0; c < nchunk; ++c) {
            int n0 = c * cs;
            int cn = (NNODES - n0 < cs) ? (NNODES - n0) : cs;
            if (cn <= 0) break;
            dim3 g(cn / 16, (NCT + 3) / 4);
            k_ygemm2<<<g, 256, 0, stream>>>(hxb, W2f, n0, Yb);
            k_edge<<<cn, 256, 0, stream>>>(ei, csr_off, csr_e, h1b, Yb, n0, agg);
        }
        k_gru<<<(NNODES * NCD) / 256, 256, 0, stream>>>(agg, indeg, Wi, Wh, bi, bh, out, hxb, r);
    }
}

// Round 4
// 1602.811 us; speedup vs baseline: 1.7470x; 1.0505x over previous
//
#include <hip/hip_runtime.h>
#include <hip/hip_bf16.h>

#define NNODES 20000
#define NEDGES 200000
#define NCD 32
#define FDIMD 13
#define FHIDD 64
#define NREPD 10
#define OUTCD (NCD * (NREPD + 1))   // 352
#define YROW 2080                   // 64*32 filter cols + 32 bias cols
#define NCT 130                     // YROW/16 col tiles
#define YPAD 2084                   // padded LDS row in bf16 units (bank spread)

typedef short bf16x8 __attribute__((ext_vector_type(8)));
typedef float f32x4 __attribute__((ext_vector_type(4)));

static __device__ __forceinline__ float bf2f(unsigned short u) {
    union { unsigned u; float f; } cv; cv.u = ((unsigned)u) << 16; return cv.f;
}

// ---------------------------------------------------------------------------
__global__ __launch_bounds__(256) void k_copy_h0(const float* __restrict__ hx,
                                                 float* __restrict__ out,
                                                 __hip_bfloat16* __restrict__ hxb) {
    int tid = blockIdx.x * 256 + threadIdx.x;
    if (tid < NNODES * NCD) {
        float v = hx[tid];
        out[(size_t)(tid >> 5) * OUTCD + (tid & 31)] = v;
        hxb[tid] = __float2bfloat16(v);
    }
}

__global__ __launch_bounds__(256) void k_degrees(const int* __restrict__ ei,
                                                 float* __restrict__ indeg,
                                                 int* __restrict__ outcnt) {
    int e = blockIdx.x * 256 + threadIdx.x;
    if (e < NEDGES) {
        atomicAdd(&indeg[ei[NEDGES + e]], 1.0f);
        atomicAdd(&outcnt[ei[e]], 1);
    }
}

__global__ __launch_bounds__(256) void k_scan(const int* __restrict__ outcnt,
                                              int* __restrict__ csr_off) {
    __shared__ int s_w[4];
    __shared__ int s_base;
    int t = threadIdx.x;
    if (t == 0) s_base = 0;
    __syncthreads();
    for (int base = 0; base < NNODES; base += 256) {
        int i = base + t;
        int v = (i < NNODES) ? outcnt[i] : 0;
        int x = v;
        #pragma unroll
        for (int d = 1; d < 64; d <<= 1) {
            int y = __shfl_up(x, d);
            if ((t & 63) >= d) x += y;
        }
        if ((t & 63) == 63) s_w[t >> 6] = x;
        __syncthreads();
        int wid = t >> 6, wb = 0;
        for (int w = 0; w < wid; ++w) wb += s_w[w];
        if (i < NNODES) csr_off[i] = s_base + wb + x - v;
        int ctot = s_w[0] + s_w[1] + s_w[2] + s_w[3];
        __syncthreads();
        if (t == 0) s_base += ctot;
        __syncthreads();
    }
    if (t == 0) csr_off[NNODES] = s_base;
}

__global__ __launch_bounds__(256) void k_fill(const int* __restrict__ ei,
                                              const int* __restrict__ csr_off,
                                              int* __restrict__ cursor,
                                              int* __restrict__ csr_e) {
    int e = blockIdx.x * 256 + threadIdx.x;
    if (e < NEDGES) {
        int s = ei[e];
        int p = atomicAdd(&cursor[s], 1);
        csr_e[csr_off[s] + p] = e;
    }
}

// ---------------------------------------------------------------------------
// h1[e,k] = relu(ef[e] @ fW1 + fb1)[k], bf16.
__global__ __launch_bounds__(256) void k_h1(const float* __restrict__ ef,
                                            const float* __restrict__ fW1,
                                            const float* __restrict__ fb1,
                                            __hip_bfloat16* __restrict__ h1b) {
    __shared__ float s_w1[FDIMD * FHIDD];
    __shared__ float s_ef[4 * FDIMD];
    int t = threadIdx.x;
    for (int idx = t; idx < FDIMD * FHIDD; idx += 256) s_w1[idx] = fW1[idx];
    if (t < 4 * FDIMD) s_ef[t] = ef[(size_t)blockIdx.x * 4 * FDIMD + t];
    __syncthreads();
    int je = t >> 6, k = t & 63;
    float v = fb1[k];
    #pragma unroll
    for (int j = 0; j < FDIMD; ++j) v += s_ef[je * FDIMD + j] * s_w1[j * FHIDD + k];
    h1b[(size_t)(blockIdx.x * 4 + je) * FHIDD + k] = __float2bfloat16(fmaxf(v, 0.f));
}

// ---------------------------------------------------------------------------
// Lane-swizzled B-fragments of W2r (rearranged fW2 + fb2 bias cols).
__global__ __launch_bounds__(256) void k_w2frag(const float* __restrict__ fW2,
                                                const float* __restrict__ fb2,
                                                __hip_bfloat16* __restrict__ W2f) {
    int idx = blockIdx.x * 256 + threadIdx.x;
    if (idx >= NCT * 64) return;
    int ct = idx >> 6, lane = idx & 63;
    int j = ct * 16 + (lane & 15);
    __align__(16) __hip_bfloat16 tmp[8];
    #pragma unroll
    for (int jj = 0; jj < 8; ++jj) {
        int i = (lane >> 4) * 8 + jj;
        float v = (j < 2048) ? fW2[(size_t)(j >> 5) * 1024 + i * 32 + (j & 31)]
                             : fb2[i * 32 + (j - 2048)];
        tmp[jj] = __float2bfloat16(v);
    }
    *reinterpret_cast<uint4*>(&W2f[(size_t)ct * 1024 + lane * 8]) =
        *reinterpret_cast<const uint4*>(tmp);
}

// GRU weights transposed once: WiT[g*32+i] = Wi[i*96+g]
__global__ __launch_bounds__(256) void k_prep(const float* __restrict__ Wi,
                                              const float* __restrict__ Wh,
                                              float* __restrict__ WiT,
                                              float* __restrict__ WhT) {
    int idx = blockIdx.x * 256 + threadIdx.x;
    if (idx < 3072) {
        int g = idx >> 5, i = idx & 31;
        WiT[idx] = Wi[i * 96 + g];
        WhT[idx] = Wh[i * 96 + g];
    }
}

// ---------------------------------------------------------------------------
// Fused: per 16-node block, (1) Y = hxb @ W2r via MFMA -> LDS (bf16),
// (2) all edges of these 16 src nodes: msg = h1 . Y-slices + bias,
// scatter-add into agg[dst]. 16 edges/batch x 16 threads x 2 outputs.
__global__ __launch_bounds__(256) void k_msg(
    const int* __restrict__ ei, const int* __restrict__ csr_off,
    const int* __restrict__ csr_e, const __hip_bfloat16* __restrict__ h1b,
    const __hip_bfloat16* __restrict__ hxb, const __hip_bfloat16* __restrict__ W2f,
    float* __restrict__ agg) {
    __shared__ __hip_bfloat16 s_Y[16 * YPAD];   // 66,688 B
    __shared__ unsigned s_h1u[16][32];          // 2 KB
    __shared__ int s_row[16], s_dst[16];
    const int t = threadIdx.x;
    const int n0 = blockIdx.x * 16;
    const int estart = csr_off[n0];
    const int eend   = csr_off[n0 + 16];
    if (estart == eend) return;   // block-uniform

    // ---- phase 1: Y tiles via MFMA into LDS
    const int lane = t & 63;
    const int wave = t >> 6;
    bf16x8 a = *reinterpret_cast<const bf16x8*>(
        hxb + (size_t)(n0 + (lane & 15)) * NCD + (lane >> 4) * 8);
    const int colw = lane & 15;
    const int rown = (lane >> 4) * 4;
    for (int ct = wave; ct < NCT; ct += 4) {
        bf16x8 b = *reinterpret_cast<const bf16x8*>(W2f + (size_t)ct * 1024 + lane * 8);
        f32x4 c = {0.f, 0.f, 0.f, 0.f};
        c = __builtin_amdgcn_mfma_f32_16x16x32_bf16(a, b, c, 0, 0, 0);
        const int j = ct * 16 + colw;
        #pragma unroll
        for (int r = 0; r < 4; ++r)
            s_Y[(rown + r) * YPAD + j] = __float2bfloat16(c[r]);
    }
    __syncthreads();

    // ---- phase 2: edges
    const unsigned* Yu  = reinterpret_cast<const unsigned*>(s_Y);
    const unsigned* h1u = reinterpret_cast<const unsigned*>(h1b);
    const int je  = t >> 4;
    const int oph = t & 15;   // outputs 2*oph, 2*oph+1
    for (int base = estart; base < eend; base += 16) {
        const int nb = min(16, eend - base);
        __syncthreads();
        if (t < nb) {
            int e = csr_e[base + t];
            s_row[t] = ei[e] - n0;
            s_dst[t] = ei[NEDGES + e];
        }
        for (int idx = t; idx < nb * 32; idx += 256) {
            int jj = idx >> 5, kk = idx & 31;
            int e = csr_e[base + jj];
            s_h1u[jj][kk] = h1u[(size_t)e * 32 + kk];
        }
        __syncthreads();
        if (je < nb) {
            const int rowd = s_row[je] * (YPAD / 2);
            float a0, a1;
            {
                unsigned bw = Yu[rowd + 1024 + oph];   // bias cols j=2048+2*oph
                a0 = bf2f((unsigned short)(bw & 0xffff));
                a1 = bf2f((unsigned short)(bw >> 16));
            }
            #pragma unroll
            for (int kk = 0; kk < 32; ++kk) {
                unsigned hw = s_h1u[je][kk];
                float h0 = bf2f((unsigned short)(hw & 0xffff));
                float h1v = bf2f((unsigned short)(hw >> 16));
                unsigned y0 = Yu[rowd + (2 * kk) * 16 + oph];
                unsigned y1 = Yu[rowd + (2 * kk + 1) * 16 + oph];
                a0 += h0 * bf2f((unsigned short)(y0 & 0xffff)) +
                      h1v * bf2f((unsigned short)(y1 & 0xffff));
                a1 += h0 * bf2f((unsigned short)(y0 >> 16)) +
                      h1v * bf2f((unsigned short)(y1 >> 16));
            }
            float* ap = &agg[(size_t)s_dst[je] * NCD + 2 * oph];
            atomicAdd(ap, a0);
            atomicAdd(ap + 1, a1);
        }
    }
}

// ---------------------------------------------------------------------------
__global__ __launch_bounds__(256) void k_gru(
    const float* __restrict__ agg, const float* __restrict__ indeg,
    const float* __restrict__ WiT, const float* __restrict__ WhT,
    const float* __restrict__ bi, const float* __restrict__ bh,
    float* __restrict__ out, __hip_bfloat16* __restrict__ hxb, int r) {
    __shared__ __align__(16) float sWiT[96 * 36];
    __shared__ __align__(16) float sWhT[96 * 36];
    __shared__ float s_x[8][32];
    __shared__ float s_h[8][32];
    const int t = threadIdx.x;
    const float4* WiT4 = reinterpret_cast<const float4*>(WiT);
    const float4* WhT4 = reinterpret_cast<const float4*>(WhT);
    for (int p = t; p < 768; p += 256) {
        int g = p >> 3, i = (p & 7) * 4;
        *reinterpret_cast<float4*>(&sWiT[g * 36 + i]) = WiT4[p];
        *reinterpret_cast<float4*>(&sWhT[g * 36 + i]) = WhT4[p];
    }
    const int tid = blockIdx.x * 256 + t;
    const int n   = tid >> 5;
    const int c   = t & 31;
    const int ln  = t >> 5;
    {
        const float invd = 1.0f / fmaxf(indeg[n], 1.0f);
        s_x[ln][c] = agg[(size_t)n * NCD + c] * invd;
        s_h[ln][c] = out[(size_t)n * OUTCD + r * NCD + c];
    }
    __syncthreads();
    float ir = bi[c], iz = bi[NCD + c], in_ = bi[2 * NCD + c];
    float hr = bh[c], hz = bh[NCD + c], hn = bh[2 * NCD + c];
    const float* wi_r = &sWiT[c * 36];
    const float* wi_z = &sWiT[(NCD + c) * 36];
    const float* wi_n = &sWiT[(2 * NCD + c) * 36];
    const float* wh_r = &sWhT[c * 36];
    const float* wh_z = &sWhT[(NCD + c) * 36];
    const float* wh_n = &sWhT[(2 * NCD + c) * 36];
    #pragma unroll
    for (int i4 = 0; i4 < 8; ++i4) {
        const float4 xx = *reinterpret_cast<const float4*>(&s_x[ln][i4 * 4]);
        const float4 hh = *reinterpret_cast<const float4*>(&s_h[ln][i4 * 4]);
        const float4 a = *reinterpret_cast<const float4*>(&wi_r[i4 * 4]);
        const float4 b = *reinterpret_cast<const float4*>(&wi_z[i4 * 4]);
        const float4 g = *reinterpret_cast<const float4*>(&wi_n[i4 * 4]);
        const float4 d = *reinterpret_cast<const float4*>(&wh_r[i4 * 4]);
        const float4 e = *reinterpret_cast<const float4*>(&wh_z[i4 * 4]);
        const float4 f = *reinterpret_cast<const float4*>(&wh_n[i4 * 4]);
        ir  += xx.x * a.x + xx.y * a.y + xx.z * a.z + xx.w * a.w;
        iz  += xx.x * b.x + xx.y * b.y + xx.z * b.z + xx.w * b.w;
        in_ += xx.x * g.x + xx.y * g.y + xx.z * g.z + xx.w * g.w;
        hr  += hh.x * d.x + hh.y * d.y + hh.z * d.z + hh.w * d.w;
        hz  += hh.x * e.x + hh.y * e.y + hh.z * e.z + hh.w * e.w;
        hn  += hh.x * f.x + hh.y * f.y + hh.z * f.z + hh.w * f.w;
    }
    const float rg = 1.f / (1.f + expf(-(ir + hr)));
    const float zg = 1.f / (1.f + expf(-(iz + hz)));
    const float ng = tanhf(in_ + rg * hn);
    const float hv = (1.f - zg) * ng + zg * s_h[ln][c];
    out[(size_t)n * OUTCD + (r + 1) * NCD + c] = hv;
    hxb[(size_t)n * NCD + c] = __float2bfloat16(hv);
}

// ---------------------------------------------------------------------------
extern "C" void kernel_launch(void* const* d_in, const int* in_sizes, int n_in,
                              void* d_out, int out_size, void* d_ws, size_t ws_size,
                              hipStream_t stream) {
    const float* hx  = (const float*)d_in[0];
    const int*   ei  = (const int*)d_in[1];
    const float* ef  = (const float*)d_in[2];
    const float* fW1 = (const float*)d_in[3];
    const float* fb1 = (const float*)d_in[4];
    const float* fW2 = (const float*)d_in[5];
    const float* fb2 = (const float*)d_in[6];
    const float* Wi  = (const float*)d_in[7];
    const float* Wh  = (const float*)d_in[8];
    const float* bi  = (const float*)d_in[9];
    const float* bh  = (const float*)d_in[10];
    float* out = (float*)d_out;

    char* ws = (char*)d_ws;
    size_t off = 0;
    auto take = [&](size_t bytes) -> void* {
        void* p = ws + off;
        off = (off + bytes + 255) & ~(size_t)255;
        return p;
    };
    __hip_bfloat16* h1b = (__hip_bfloat16*)take((size_t)NEDGES * FHIDD * 2);  // 25.6 MB
    __hip_bfloat16* hxb = (__hip_bfloat16*)take((size_t)NNODES * NCD * 2);    // 1.28 MB
    __hip_bfloat16* W2f = (__hip_bfloat16*)take((size_t)NCT * 1024 * 2);      // 266 KB
    float* agg    = (float*)take((size_t)NNODES * NCD * 4);                   // 2.56 MB
    float* indeg  = (float*)take((size_t)NNODES * 4);
    int*   outcnt = (int*)take((size_t)NNODES * 4);
    int*   csr_off= (int*)take((size_t)(NNODES + 1) * 4);
    int*   csr_e  = (int*)take((size_t)NEDGES * 4);
    int*   cursor = (int*)take((size_t)NNODES * 4);
    float* WiT    = (float*)take(3072 * 4);
    float* WhT    = (float*)take(3072 * 4);

    hipMemsetAsync(indeg,  0, (size_t)NNODES * 4, stream);
    hipMemsetAsync(outcnt, 0, (size_t)NNODES * 4, stream);
    hipMemsetAsync(cursor, 0, (size_t)NNODES * 4, stream);
    k_copy_h0<<<(NNODES * NCD) / 256, 256, 0, stream>>>(hx, out, hxb);
    k_degrees<<<(NEDGES + 255) / 256, 256, 0, stream>>>(ei, indeg, outcnt);
    k_scan<<<1, 256, 0, stream>>>(outcnt, csr_off);
    k_fill<<<(NEDGES + 255) / 256, 256, 0, stream>>>(ei, csr_off, cursor, csr_e);
    k_h1<<<NEDGES / 4, 256, 0, stream>>>(ef, fW1, fb1, h1b);
    k_w2frag<<<(NCT * 64 + 255) / 256, 256, 0, stream>>>(fW2, fb2, W2f);
    k_prep<<<12, 256, 0, stream>>>(Wi, Wh, WiT, WhT);

    for (int r = 0; r < NREPD; ++r) {
        hipMemsetAsync(agg, 0, (size_t)NNODES * NCD * 4, stream);
        k_msg<<<NNODES / 16, 256, 0, stream>>>(ei, csr_off, csr_e, h1b, hxb, W2f, agg);
        k_gru<<<(NNODES * NCD) / 256, 256, 0, stream>>>(agg, indeg, WiT, WhT, bi, bh, out, hxb, r);
    }
}

// Round 6
// 1328.575 us; speedup vs baseline: 2.1076x; 1.2064x over previous
//
#include <hip/hip_runtime.h>
#include <hip/hip_bf16.h>

#define NNODES 20000
#define NEDGES 200000
#define NCD 32
#define FDIMD 13
#define FHIDD 64
#define NREPD 10
#define OUTCD (NCD * (NREPD + 1))   // 352
#define NCT 130                     // (64*32 + 32 bias) / 16 col tiles
#define NPB 8                       // nodes per k_msg block
#define OST 34                      // Ykp o-stride in u32 (pad 32->34)
#define NST (32 * OST)              // Ykp node stride in u32 (1088)

typedef short bf16x8 __attribute__((ext_vector_type(8)));
typedef float f32x4 __attribute__((ext_vector_type(4)));

static __device__ __forceinline__ float u2f(unsigned u) {
    union { unsigned u; float f; } cv; cv.u = u; return cv.f;
}

// ---------------------------------------------------------------------------
__global__ __launch_bounds__(256) void k_copy_h0(const float* __restrict__ hx,
                                                 float* __restrict__ out,
                                                 __hip_bfloat16* __restrict__ hxb) {
    int tid = blockIdx.x * 256 + threadIdx.x;
    if (tid < NNODES * NCD) {
        float v = hx[tid];
        out[(size_t)(tid >> 5) * OUTCD + (tid & 31)] = v;
        hxb[tid] = __float2bfloat16(v);
    }
}

__global__ __launch_bounds__(256) void k_degrees(const int* __restrict__ ei,
                                                 float* __restrict__ indeg,
                                                 int* __restrict__ outcnt) {
    int e = blockIdx.x * 256 + threadIdx.x;
    if (e < NEDGES) {
        atomicAdd(&indeg[ei[NEDGES + e]], 1.0f);
        atomicAdd(&outcnt[ei[e]], 1);
    }
}

__global__ __launch_bounds__(256) void k_scan(const int* __restrict__ outcnt,
                                              int* __restrict__ csr_off) {
    __shared__ int s_w[4];
    __shared__ int s_base;
    int t = threadIdx.x;
    if (t == 0) s_base = 0;
    __syncthreads();
    for (int base = 0; base < NNODES; base += 256) {
        int i = base + t;
        int v = (i < NNODES) ? outcnt[i] : 0;
        int x = v;
        #pragma unroll
        for (int d = 1; d < 64; d <<= 1) {
            int y = __shfl_up(x, d);
            if ((t & 63) >= d) x += y;
        }
        if ((t & 63) == 63) s_w[t >> 6] = x;
        __syncthreads();
        int wid = t >> 6, wb = 0;
        for (int w = 0; w < wid; ++w) wb += s_w[w];
        if (i < NNODES) csr_off[i] = s_base + wb + x - v;
        int ctot = s_w[0] + s_w[1] + s_w[2] + s_w[3];
        __syncthreads();
        if (t == 0) s_base += ctot;
        __syncthreads();
    }
    if (t == 0) csr_off[NNODES] = s_base;
}

// also records rank[e] = sorted position of edge e
__global__ __launch_bounds__(256) void k_fill(const int* __restrict__ ei,
                                              const int* __restrict__ csr_off,
                                              int* __restrict__ cursor,
                                              int* __restrict__ csr_e,
                                              int* __restrict__ rank) {
    int e = blockIdx.x * 256 + threadIdx.x;
    if (e < NEDGES) {
        int s = ei[e];
        int p = atomicAdd(&cursor[s], 1);
        int pos = csr_off[s] + p;
        csr_e[pos] = e;
        rank[e] = pos;
    }
}

// srcs/dsts in CSR position order
__global__ __launch_bounds__(256) void k_reord(const int* __restrict__ ei,
                                               const int* __restrict__ csr_e,
                                               int* __restrict__ srcs,
                                               int* __restrict__ dsts) {
    int pos = blockIdx.x * 256 + threadIdx.x;
    if (pos < NEDGES) {
        int e = csr_e[pos];
        srcs[pos] = ei[e];
        dsts[pos] = ei[NEDGES + e];
    }
}

// ---------------------------------------------------------------------------
// h1s[rank[e], k] = relu(ef[e] @ fW1 + fb1)[k], bf16, CSR-position order.
__global__ __launch_bounds__(256) void k_h1(const float* __restrict__ ef,
                                            const float* __restrict__ fW1,
                                            const float* __restrict__ fb1,
                                            const int* __restrict__ rank,
                                            __hip_bfloat16* __restrict__ h1s) {
    __shared__ float s_w1[FDIMD * FHIDD];
    __shared__ float s_ef[4 * FDIMD];
    __shared__ int s_rk[4];
    int t = threadIdx.x;
    for (int idx = t; idx < FDIMD * FHIDD; idx += 256) s_w1[idx] = fW1[idx];
    if (t < 4 * FDIMD) s_ef[t] = ef[(size_t)blockIdx.x * 4 * FDIMD + t];
    if (t < 4) s_rk[t] = rank[blockIdx.x * 4 + t];
    __syncthreads();
    int je = t >> 6, k = t & 63;
    float v = fb1[k];
    #pragma unroll
    for (int j = 0; j < FDIMD; ++j) v += s_ef[je * FDIMD + j] * s_w1[j * FHIDD + k];
    h1s[(size_t)s_rk[je] * FHIDD + k] = __float2bfloat16(fmaxf(v, 0.f));
}

// ---------------------------------------------------------------------------
// Lane-swizzled B-fragments of W2r (rearranged fW2 + fb2 bias cols).
__global__ __launch_bounds__(256) void k_w2frag(const float* __restrict__ fW2,
                                                const float* __restrict__ fb2,
                                                __hip_bfloat16* __restrict__ W2f) {
    int idx = blockIdx.x * 256 + threadIdx.x;
    if (idx >= NCT * 64) return;
    int ct = idx >> 6, lane = idx & 63;
    int j = ct * 16 + (lane & 15);
    __align__(16) __hip_bfloat16 tmp[8];
    #pragma unroll
    for (int jj = 0; jj < 8; ++jj) {
        int i = (lane >> 4) * 8 + jj;
        float v = (j < 2048) ? fW2[(size_t)(j >> 5) * 1024 + i * 32 + (j & 31)]
                             : fb2[i * 32 + (j - 2048)];
        tmp[jj] = __float2bfloat16(v);
    }
    *reinterpret_cast<uint4*>(&W2f[(size_t)ct * 1024 + lane * 8]) =
        *reinterpret_cast<const uint4*>(tmp);
}

// GRU weights transposed once: WiT[g*32+i] = Wi[i*96+g]
__global__ __launch_bounds__(256) void k_prep(const float* __restrict__ Wi,
                                              const float* __restrict__ Wh,
                                              float* __restrict__ WiT,
                                              float* __restrict__ WhT) {
    int idx = blockIdx.x * 256 + threadIdx.x;
    if (idx < 3072) {
        int g = idx >> 5, i = idx & 31;
        WiT[idx] = Wi[i * 96 + g];
        WhT[idx] = Wh[i * 96 + g];
    }
}

// ---------------------------------------------------------------------------
// Fused per 8-node block:
//  phase 1: Y = hxb @ W2r via MFMA -> LDS, k-pair-packed transposed:
//           Ykp[n][o][kk] = u32(Y[2kk][o] | Y[2kk+1][o]<<16); bias f32.
//  phase 2: contiguous sorted edge batches of 16; 16 threads/edge, 2 outputs;
//           b128 Y reads + packed-bf16 unpack FMA; scatter-add to agg.
__global__ __launch_bounds__(256) void k_msg(
    const int* __restrict__ csr_off, const int* __restrict__ srcs,
    const int* __restrict__ dsts, const __hip_bfloat16* __restrict__ h1s,
    const __hip_bfloat16* __restrict__ hxb, const __hip_bfloat16* __restrict__ W2f,
    float* __restrict__ agg) {
    __shared__ unsigned sYk[NPB * NST];      // 34,816 B
    __shared__ float s_bias[NPB][32];        // 1 KB
    __shared__ uint4 sH1[16 * 8];            // 2 KB
    __shared__ int s_dst[16], s_row[16];
    const int t = threadIdx.x;
    const int n0 = blockIdx.x * NPB;
    const int estart = csr_off[n0];
    const int eend   = csr_off[n0 + NPB];
    if (estart == eend) return;   // block-uniform

    // ---- phase 1
    const int lane = t & 63;
    const int wave = t >> 6;
    const int arow = (lane & 15) < NPB ? (lane & 15) : (NPB - 1);  // clamp pad rows
    bf16x8 a = *reinterpret_cast<const bf16x8*>(
        hxb + (size_t)(n0 + arow) * NCD + (lane >> 4) * 8);
    const int colw = lane & 15;
    const int rbase = (lane >> 4) * 4;
    unsigned short* sYk16 = reinterpret_cast<unsigned short*>(sYk);
    for (int ct = wave; ct < NCT; ct += 4) {
        bf16x8 b = *reinterpret_cast<const bf16x8*>(W2f + (size_t)ct * 1024 + lane * 8);
        f32x4 c = {0.f, 0.f, 0.f, 0.f};
        c = __builtin_amdgcn_mfma_f32_16x16x32_bf16(a, b, c, 0, 0, 0);
        if (rbase < NPB) {        // lanes holding valid rows 0..7
            const int j = ct * 16 + colw;
            if (j < 2048) {
                const int k = j >> 5, o = j & 31;
                const int ub = o * (2 * OST) + (k >> 1) * 2 + (k & 1);
                #pragma unroll
                for (int r = 0; r < 4; ++r)
                    sYk16[(rbase + r) * (2 * NST) + ub] =
                        (unsigned short)(__bfloat16_as_ushort(__float2bfloat16(c[r])));
            } else {
                const int o = j - 2048;
                #pragma unroll
                for (int r = 0; r < 4; ++r) s_bias[rbase + r][o] = c[r];
            }
        }
    }

    // ---- phase 2
    const uint4* h1s4 = reinterpret_cast<const uint4*>(h1s);
    const int je  = t >> 4;
    const int oph = t & 15;
    for (int base = estart; base < eend; base += 16) {
        const int nb = min(16, eend - base);
        __syncthreads();
        if (t < nb) {
            s_dst[t] = dsts[base + t];
            s_row[t] = srcs[base + t] - n0;
        }
        if (t < nb * 8) sH1[t] = h1s4[(size_t)base * 8 + t];
        __syncthreads();
        if (je < nb) {
            const int row = s_row[je];
            const unsigned* y0 = &sYk[row * NST + (2 * oph) * OST];
            const unsigned* y1 = y0 + OST;
            float a0 = s_bias[row][2 * oph];
            float a1 = s_bias[row][2 * oph + 1];
            #pragma unroll
            for (int c = 0; c < 8; ++c) {
                const uint4 hq = sH1[je * 8 + c];
                const uint4 w0 = *reinterpret_cast<const uint4*>(&y0[c * 4]);
                const uint4 w1 = *reinterpret_cast<const uint4*>(&y1[c * 4]);
                const unsigned hv[4] = {hq.x, hq.y, hq.z, hq.w};
                const unsigned v0[4] = {w0.x, w0.y, w0.z, w0.w};
                const unsigned v1[4] = {w1.x, w1.y, w1.z, w1.w};
                #pragma unroll
                for (int i = 0; i < 4; ++i) {
                    const float hl = u2f(hv[i] << 16);
                    const float hh = u2f(hv[i] & 0xffff0000u);
                    a0 += hl * u2f(v0[i] << 16) + hh * u2f(v0[i] & 0xffff0000u);
                    a1 += hl * u2f(v1[i] << 16) + hh * u2f(v1[i] & 0xffff0000u);
                }
            }
            float* ap = &agg[(size_t)s_dst[je] * NCD + 2 * oph];
            atomicAdd(ap, a0);
            atomicAdd(ap + 1, a1);
        }
    }
}

// ---------------------------------------------------------------------------
__global__ __launch_bounds__(256) void k_gru(
    const float* __restrict__ agg, const float* __restrict__ indeg,
    const float* __restrict__ WiT, const float* __restrict__ WhT,
    const float* __restrict__ bi, const float* __restrict__ bh,
    float* __restrict__ out, __hip_bfloat16* __restrict__ hxb, int r) {
    __shared__ __align__(16) float sWiT[96 * 36];
    __shared__ __align__(16) float sWhT[96 * 36];
    __shared__ float s_x[8][32];
    __shared__ float s_h[8][32];
    const int t = threadIdx.x;
    const float4* WiT4 = reinterpret_cast<const float4*>(WiT);
    const float4* WhT4 = reinterpret_cast<const float4*>(WhT);
    for (int p = t; p < 768; p += 256) {
        int g = p >> 3, i = (p & 7) * 4;
        *reinterpret_cast<float4*>(&sWiT[g * 36 + i]) = WiT4[p];
        *reinterpret_cast<float4*>(&sWhT[g * 36 + i]) = WhT4[p];
    }
    const int tid = blockIdx.x * 256 + t;
    const int n   = tid >> 5;
    const int c   = t & 31;
    const int ln  = t >> 5;
    {
        const float invd = 1.0f / fmaxf(indeg[n], 1.0f);
        s_x[ln][c] = agg[(size_t)n * NCD + c] * invd;
        s_h[ln][c] = out[(size_t)n * OUTCD + r * NCD + c];
    }
    __syncthreads();
    float ir = bi[c], iz = bi[NCD + c], in_ = bi[2 * NCD + c];
    float hr = bh[c], hz = bh[NCD + c], hn = bh[2 * NCD + c];
    const float* wi_r = &sWiT[c * 36];
    const float* wi_z = &sWiT[(NCD + c) * 36];
    const float* wi_n = &sWiT[(2 * NCD + c) * 36];
    const float* wh_r = &sWhT[c * 36];
    const float* wh_z = &sWhT[(NCD + c) * 36];
    const float* wh_n = &sWhT[(2 * NCD + c) * 36];
    #pragma unroll
    for (int i4 = 0; i4 < 8; ++i4) {
        const float4 xx = *reinterpret_cast<const float4*>(&s_x[ln][i4 * 4]);
        const float4 hh = *reinterpret_cast<const float4*>(&s_h[ln][i4 * 4]);
        const float4 a = *reinterpret_cast<const float4*>(&wi_r[i4 * 4]);
        const float4 b = *reinterpret_cast<const float4*>(&wi_z[i4 * 4]);
        const float4 g = *reinterpret_cast<const float4*>(&wi_n[i4 * 4]);
        const float4 d = *reinterpret_cast<const float4*>(&wh_r[i4 * 4]);
        const float4 e = *reinterpret_cast<const float4*>(&wh_z[i4 * 4]);
        const float4 f = *reinterpret_cast<const float4*>(&wh_n[i4 * 4]);
        ir  += xx.x * a.x + xx.y * a.y + xx.z * a.z + xx.w * a.w;
        iz  += xx.x * b.x + xx.y * b.y + xx.z * b.z + xx.w * b.w;
        in_ += xx.x * g.x + xx.y * g.y + xx.z * g.z + xx.w * g.w;
        hr  += hh.x * d.x + hh.y * d.y + hh.z * d.z + hh.w * d.w;
        hz  += hh.x * e.x + hh.y * e.y + hh.z * e.z + hh.w * e.w;
        hn  += hh.x * f.x + hh.y * f.y + hh.z * f.z + hh.w * f.w;
    }
    const float rg = 1.f / (1.f + expf(-(ir + hr)));
    const float zg = 1.f / (1.f + expf(-(iz + hz)));
    const float ng = tanhf(in_ + rg * hn);
    const float hv = (1.f - zg) * ng + zg * s_h[ln][c];
    out[(size_t)n * OUTCD + (r + 1) * NCD + c] = hv;
    hxb[(size_t)n * NCD + c] = __float2bfloat16(hv);
}

// ---------------------------------------------------------------------------
extern "C" void kernel_launch(void* const* d_in, const int* in_sizes, int n_in,
                              void* d_out, int out_size, void* d_ws, size_t ws_size,
                              hipStream_t stream) {
    const float* hx  = (const float*)d_in[0];
    const int*   ei  = (const int*)d_in[1];
    const float* ef  = (const float*)d_in[2];
    const float* fW1 = (const float*)d_in[3];
    const float* fb1 = (const float*)d_in[4];
    const float* fW2 = (const float*)d_in[5];
    const float* fb2 = (const float*)d_in[6];
    const float* Wi  = (const float*)d_in[7];
    const float* Wh  = (const float*)d_in[8];
    const float* bi  = (const float*)d_in[9];
    const float* bh  = (const float*)d_in[10];
    float* out = (float*)d_out;

    char* ws = (char*)d_ws;
    size_t off = 0;
    auto take = [&](size_t bytes) -> void* {
        void* p = ws + off;
        off = (off + bytes + 255) & ~(size_t)255;
        return p;
    };
    __hip_bfloat16* h1s = (__hip_bfloat16*)take((size_t)NEDGES * FHIDD * 2);  // 25.6 MB
    __hip_bfloat16* hxb = (__hip_bfloat16*)take((size_t)NNODES * NCD * 2);    // 1.28 MB
    __hip_bfloat16* W2f = (__hip_bfloat16*)take((size_t)NCT * 1024 * 2);      // 266 KB
    float* agg    = (float*)take((size_t)NNODES * NCD * 4);                   // 2.56 MB
    float* indeg  = (float*)take((size_t)NNODES * 4);
    int*   outcnt = (int*)take((size_t)NNODES * 4);
    int*   csr_off= (int*)take((size_t)(NNODES + 1) * 4);
    int*   csr_e  = (int*)take((size_t)NEDGES * 4);
    int*   cursor = (int*)take((size_t)NNODES * 4);
    int*   rank   = (int*)take((size_t)NEDGES * 4);
    int*   srcs   = (int*)take((size_t)NEDGES * 4);
    int*   dsts   = (int*)take((size_t)NEDGES * 4);
    float* WiT    = (float*)take(3072 * 4);
    float* WhT    = (float*)take(3072 * 4);

    hipMemsetAsync(indeg,  0, (size_t)NNODES * 4, stream);
    hipMemsetAsync(outcnt, 0, (size_t)NNODES * 4, stream);
    hipMemsetAsync(cursor, 0, (size_t)NNODES * 4, stream);
    k_copy_h0<<<(NNODES * NCD) / 256, 256, 0, stream>>>(hx, out, hxb);
    k_degrees<<<(NEDGES + 255) / 256, 256, 0, stream>>>(ei, indeg, outcnt);
    k_scan<<<1, 256, 0, stream>>>(outcnt, csr_off);
    k_fill<<<(NEDGES + 255) / 256, 256, 0, stream>>>(ei, csr_off, cursor, csr_e, rank);
    k_reord<<<(NEDGES + 255) / 256, 256, 0, stream>>>(ei, csr_e, srcs, dsts);
    k_h1<<<NEDGES / 4, 256, 0, stream>>>(ef, fW1, fb1, rank, h1s);
    k_w2frag<<<(NCT * 64 + 255) / 256, 256, 0, stream>>>(fW2, fb2, W2f);
    k_prep<<<12, 256, 0, stream>>>(Wi, Wh, WiT, WhT);

    for (int r = 0; r < NREPD; ++r) {
        hipMemsetAsync(agg, 0, (size_t)NNODES * NCD * 4, stream);
        k_msg<<<NNODES / NPB, 256, 0, stream>>>(csr_off, srcs, dsts, h1s, hxb, W2f, agg);
        k_gru<<<(NNODES * NCD) / 256, 256, 0, stream>>>(agg, indeg, WiT, WhT, bi, bh, out, hxb, r);
    }
}

// Round 9
// 1026.598 us; speedup vs baseline: 2.7275x; 1.2942x over previous
//
#include <hip/hip_runtime.h>
#include <hip/hip_bf16.h>

#define NNODES 20000
#define NEDGES 200000
#define NCD 32
#define FDIMD 13
#define FHIDD 64
#define NREPD 10
#define OUTCD (NCD * (NREPD + 1))   // 352
#define NCT 130                     // (64*32 + 32 bias) / 16 col tiles
#define NPB 8                       // nodes per k_msg block
#define NBLK (NNODES / NPB)         // 2500
#define MAXTILES 40000
#define YKST 72                     // sY k-stride in u16 (64 + 8 pad, 144B)
#define YNST (32 * YKST)            // sY node stride in u16 (2304)

typedef short bf16x8 __attribute__((ext_vector_type(8)));
typedef float f32x4 __attribute__((ext_vector_type(4)));

// ---------------------------------------------------------------------------
__global__ __launch_bounds__(256) void k_copy_h0(const float* __restrict__ hx,
                                                 float* __restrict__ out,
                                                 __hip_bfloat16* __restrict__ hxb) {
    int tid = blockIdx.x * 256 + threadIdx.x;
    if (tid < NNODES * NCD) {
        float v = hx[tid];
        out[(size_t)(tid >> 5) * OUTCD + (tid & 31)] = v;
        hxb[tid] = __float2bfloat16(v);
    }
}

__global__ __launch_bounds__(256) void k_degrees(const int* __restrict__ ei,
                                                 float* __restrict__ indeg,
                                                 int* __restrict__ outcnt) {
    int e = blockIdx.x * 256 + threadIdx.x;
    if (e < NEDGES) {
        atomicAdd(&indeg[ei[NEDGES + e]], 1.0f);
        atomicAdd(&outcnt[ei[e]], 1);
    }
}

// exclusive scan (generic length), single block
__global__ __launch_bounds__(256) void k_scan(const int* __restrict__ in,
                                              int* __restrict__ out, int n) {
    __shared__ int s_w[4];
    __shared__ int s_base;
    int t = threadIdx.x;
    if (t == 0) s_base = 0;
    __syncthreads();
    for (int base = 0; base < n; base += 256) {
        int i = base + t;
        int v = (i < n) ? in[i] : 0;
        int x = v;
        #pragma unroll
        for (int d = 1; d < 64; d <<= 1) {
            int y = __shfl_up(x, d);
            if ((t & 63) >= d) x += y;
        }
        if ((t & 63) == 63) s_w[t >> 6] = x;
        __syncthreads();
        int wid = t >> 6, wb = 0;
        for (int w = 0; w < wid; ++w) wb += s_w[w];
        if (i < n) out[i] = s_base + wb + x - v;
        int ctot = s_w[0] + s_w[1] + s_w[2] + s_w[3];
        __syncthreads();
        if (t == 0) s_base += ctot;
        __syncthreads();
    }
    if (t == 0) out[n] = s_base;
}

// also records rank[e] = sorted position of edge e
__global__ __launch_bounds__(256) void k_fill(const int* __restrict__ ei,
                                              const int* __restrict__ csr_off,
                                              int* __restrict__ cursor,
                                              int* __restrict__ rank) {
    int e = blockIdx.x * 256 + threadIdx.x;
    if (e < NEDGES) {
        int s = ei[e];
        int p = atomicAdd(&cursor[s], 1);
        rank[e] = csr_off[s] + p;
    }
}

// dsts in CSR position order
__global__ __launch_bounds__(256) void k_reord(const int* __restrict__ ei,
                                               const int* __restrict__ rank,
                                               int* __restrict__ dsts) {
    int e = blockIdx.x * 256 + threadIdx.x;
    if (e < NEDGES) dsts[rank[e]] = ei[NEDGES + e];
}

// per-block (8-node) tile counts: sum ceil(deg/16)
__global__ __launch_bounds__(256) void k_tcnt(const int* __restrict__ csr_off,
                                              int* __restrict__ tcnt) {
    int b = blockIdx.x * 256 + threadIdx.x;
    if (b < NBLK) {
        int s = 0;
        for (int j = 0; j < NPB; ++j) {
            int d = csr_off[b * NPB + j + 1] - csr_off[b * NPB + j];
            s += (d + 15) >> 4;
        }
        tcnt[b] = s;
    }
}

// tiles[]: packed (start<<8 | cnt<<3 | local_row)
__global__ __launch_bounds__(256) void k_tfill(const int* __restrict__ csr_off,
                                               const int* __restrict__ tile_off,
                                               unsigned* __restrict__ tiles) {
    int b = blockIdx.x * 256 + threadIdx.x;
    if (b < NBLK) {
        int off = tile_off[b];
        for (int j = 0; j < NPB; ++j) {
            int s0 = csr_off[b * NPB + j];
            int d  = csr_off[b * NPB + j + 1] - s0;
            for (int q = 0; q < d; q += 16) {
                int cnt = d - q; if (cnt > 16) cnt = 16;
                tiles[off++] = ((unsigned)(s0 + q) << 8) | ((unsigned)cnt << 3) | (unsigned)j;
            }
        }
    }
}

// ---------------------------------------------------------------------------
// h1s[rank[e], k] = relu(ef[e] @ fW1 + fb1)[k], bf16, CSR-position order.
__global__ __launch_bounds__(256) void k_h1(const float* __restrict__ ef,
                                            const float* __restrict__ fW1,
                                            const float* __restrict__ fb1,
                                            const int* __restrict__ rank,
                                            __hip_bfloat16* __restrict__ h1s) {
    __shared__ float s_w1[FDIMD * FHIDD];
    __shared__ float s_ef[4 * FDIMD];
    __shared__ int s_rk[4];
    int t = threadIdx.x;
    for (int idx = t; idx < FDIMD * FHIDD; idx += 256) s_w1[idx] = fW1[idx];
    if (t < 4 * FDIMD) s_ef[t] = ef[(size_t)blockIdx.x * 4 * FDIMD + t];
    if (t < 4) s_rk[t] = rank[blockIdx.x * 4 + t];
    __syncthreads();
    int je = t >> 6, k = t & 63;
    float v = fb1[k];
    #pragma unroll
    for (int j = 0; j < FDIMD; ++j) v += s_ef[je * FDIMD + j] * s_w1[j * FHIDD + k];
    h1s[(size_t)s_rk[je] * FHIDD + k] = __float2bfloat16(fmaxf(v, 0.f));
}

// ---------------------------------------------------------------------------
// Lane-swizzled B-fragments of W2r (rearranged fW2 + fb2 bias cols).
__global__ __launch_bounds__(256) void k_w2frag(const float* __restrict__ fW2,
                                                const float* __restrict__ fb2,
                                                __hip_bfloat16* __restrict__ W2f) {
    int idx = blockIdx.x * 256 + threadIdx.x;
    if (idx >= NCT * 64) return;
    int ct = idx >> 6, lane = idx & 63;
    int j = ct * 16 + (lane & 15);
    __align__(16) __hip_bfloat16 tmp[8];
    #pragma unroll
    for (int jj = 0; jj < 8; ++jj) {
        int i = (lane >> 4) * 8 + jj;
        float v = (j < 2048) ? fW2[(size_t)(j >> 5) * 1024 + i * 32 + (j & 31)]
                             : fb2[i * 32 + (j - 2048)];
        tmp[jj] = __float2bfloat16(v);
    }
    *reinterpret_cast<uint4*>(&W2f[(size_t)ct * 1024 + lane * 8]) =
        *reinterpret_cast<const uint4*>(tmp);
}

// GRU weights transposed once: WiT[g*32+i] = Wi[i*96+g]
__global__ __launch_bounds__(256) void k_prep(const float* __restrict__ Wi,
                                              const float* __restrict__ Wh,
                                              float* __restrict__ WiT,
                                              float* __restrict__ WhT) {
    int idx = blockIdx.x * 256 + threadIdx.x;
    if (idx < 3072) {
        int g = idx >> 5, i = idx & 31;
        WiT[idx] = Wi[i * 96 + g];
        WhT[idx] = Wh[i * 96 + g];
    }
}

// ---------------------------------------------------------------------------
// Fused per 8-node block:
//  phase 1: Y = hxb @ W2r via MFMA -> LDS, [node][o][k] layout (k contiguous);
//           bias (j>=2048) kept f32.
//  phase 2: per-wave autonomous loop over <=16-edge src tiles:
//           msg[16e x 32o] = H1[16x64] @ Y_src via 4 MFMAs; bias in acc init;
//           masked f32 atomics into agg[dst]. ONE barrier total, no staging.
__global__ __launch_bounds__(256) void k_msg(
    const int* __restrict__ tile_off, const unsigned* __restrict__ tiles,
    const int* __restrict__ dsts, const __hip_bfloat16* __restrict__ h1s,
    const __hip_bfloat16* __restrict__ hxb, const __hip_bfloat16* __restrict__ W2f,
    float* __restrict__ agg) {
    __shared__ __align__(16) unsigned short sY[NPB * YNST];  // 36,864 B
    __shared__ float s_bias[NPB][32];                        // 1 KB
    const int t = threadIdx.x, lane = t & 63, wave = t >> 6;
    const int bid = blockIdx.x;
    const int t0 = tile_off[bid], t1 = tile_off[bid + 1];
    if (t0 == t1) return;
    const int n0 = bid * NPB;

    // ---- phase 1
    const int arow = (lane & 15) < NPB ? (lane & 15) : (NPB - 1);
    bf16x8 a = *reinterpret_cast<const bf16x8*>(
        hxb + (size_t)(n0 + arow) * NCD + (lane >> 4) * 8);
    const int colw = lane & 15, rbase = (lane >> 4) * 4;
    for (int ct = wave; ct < NCT; ct += 4) {
        bf16x8 b = *reinterpret_cast<const bf16x8*>(W2f + (size_t)ct * 1024 + lane * 8);
        f32x4 c = {0.f, 0.f, 0.f, 0.f};
        c = __builtin_amdgcn_mfma_f32_16x16x32_bf16(a, b, c, 0, 0, 0);
        if (rbase < NPB) {
            const int j = ct * 16 + colw;
            if (j < 2048) {
                const int k = j >> 5, o = j & 31;
                #pragma unroll
                for (int r = 0; r < 4; ++r)
                    sY[(rbase + r) * YNST + o * YKST + k] =
                        __bfloat16_as_ushort(__float2bfloat16(c[r]));
            } else {
                const int o = j - 2048;
                #pragma unroll
                for (int r = 0; r < 4; ++r) s_bias[rbase + r][o] = c[r];
            }
        }
    }
    __syncthreads();

    // ---- phase 2 (per-wave, no barriers)
    const int oc = lane & 15, ks = lane >> 4;
    for (int ti = t0 + wave; ti < t1; ti += 4) {
        const unsigned T = tiles[ti];
        const int start = (int)(T >> 8);
        const int cnt   = (int)((T >> 3) & 31);
        const int row   = (int)(T & 7);
        long eidx = start + oc;
        if (eidx > NEDGES - 1) eidx = NEDGES - 1;
        const bf16x8 a0 = *reinterpret_cast<const bf16x8*>(h1s + eidx * 64 + ks * 8);
        const bf16x8 a1 = *reinterpret_cast<const bf16x8*>(h1s + eidx * 64 + 32 + ks * 8);
        #pragma unroll
        for (int ct = 0; ct < 2; ++ct) {
            const int o = ct * 16 + oc;
            const unsigned short* yp = sY + row * YNST + o * YKST;
            const bf16x8 b0 = *reinterpret_cast<const bf16x8*>(yp + ks * 8);
            const bf16x8 b1 = *reinterpret_cast<const bf16x8*>(yp + 32 + ks * 8);
            const float bias = s_bias[row][o];
            f32x4 acc = {bias, bias, bias, bias};
            acc = __builtin_amdgcn_mfma_f32_16x16x32_bf16(a0, b0, acc, 0, 0, 0);
            acc = __builtin_amdgcn_mfma_f32_16x16x32_bf16(a1, b1, acc, 0, 0, 0);
            #pragma unroll
            for (int r = 0; r < 4; ++r) {
                const int slot = ks * 4 + r;
                if (slot < cnt)
                    atomicAdd(&agg[(size_t)dsts[start + slot] * NCD + o], acc[r]);
            }
        }
    }
}

// ---------------------------------------------------------------------------
__global__ __launch_bounds__(256) void k_gru(
    const float* __restrict__ agg, const float* __restrict__ indeg,
    const float* __restrict__ WiT, const float* __restrict__ WhT,
    const float* __restrict__ bi, const float* __restrict__ bh,
    float* __restrict__ out, __hip_bfloat16* __restrict__ hxb, int r) {
    __shared__ __align__(16) float sWiT[96 * 36];
    __shared__ __align__(16) float sWhT[96 * 36];
    __shared__ float s_x[8][32];
    __shared__ float s_h[8][32];
    const int t = threadIdx.x;
    const float4* WiT4 = reinterpret_cast<const float4*>(WiT);
    const float4* WhT4 = reinterpret_cast<const float4*>(WhT);
    for (int p = t; p < 768; p += 256) {
        int g = p >> 3, i = (p & 7) * 4;
        *reinterpret_cast<float4*>(&sWiT[g * 36 + i]) = WiT4[p];
        *reinterpret_cast<float4*>(&sWhT[g * 36 + i]) = WhT4[p];
    }
    const int tid = blockIdx.x * 256 + t;
    const int n   = tid >> 5;
    const int c   = t & 31;
    const int ln  = t >> 5;
    {
        const float invd = 1.0f / fmaxf(indeg[n], 1.0f);
        s_x[ln][c] = agg[(size_t)n * NCD + c] * invd;
        s_h[ln][c] = out[(size_t)n * OUTCD + r * NCD + c];
    }
    __syncthreads();
    float ir = bi[c], iz = bi[NCD + c], in_ = bi[2 * NCD + c];
    float hr = bh[c], hz = bh[NCD + c], hn = bh[2 * NCD + c];
    const float* wi_r = &sWiT[c * 36];
    const float* wi_z = &sWiT[(NCD + c) * 36];
    const float* wi_n = &sWiT[(2 * NCD + c) * 36];
    const float* wh_r = &sWhT[c * 36];
    const float* wh_z = &sWhT[(NCD + c) * 36];
    const float* wh_n = &sWhT[(2 * NCD + c) * 36];
    #pragma unroll
    for (int i4 = 0; i4 < 8; ++i4) {
        const float4 xx = *reinterpret_cast<const float4*>(&s_x[ln][i4 * 4]);
        const float4 hh = *reinterpret_cast<const float4*>(&s_h[ln][i4 * 4]);
        const float4 a = *reinterpret_cast<const float4*>(&wi_r[i4 * 4]);
        const float4 b = *reinterpret_cast<const float4*>(&wi_z[i4 * 4]);
        const float4 g = *reinterpret_cast<const float4*>(&wi_n[i4 * 4]);
        const float4 d = *reinterpret_cast<const float4*>(&wh_r[i4 * 4]);
        const float4 e = *reinterpret_cast<const float4*>(&wh_z[i4 * 4]);
        const float4 f = *reinterpret_cast<const float4*>(&wh_n[i4 * 4]);
        ir  += xx.x * a.x + xx.y * a.y + xx.z * a.z + xx.w * a.w;
        iz  += xx.x * b.x + xx.y * b.y + xx.z * b.z + xx.w * b.w;
        in_ += xx.x * g.x + xx.y * g.y + xx.z * g.z + xx.w * g.w;
        hr  += hh.x * d.x + hh.y * d.y + hh.z * d.z + hh.w * d.w;
        hz  += hh.x * e.x + hh.y * e.y + hh.z * e.z + hh.w * e.w;
        hn  += hh.x * f.x + hh.y * f.y + hh.z * f.z + hh.w * f.w;
    }
    const float rg = 1.f / (1.f + expf(-(ir + hr)));
    const float zg = 1.f / (1.f + expf(-(iz + hz)));
    const float ng = tanhf(in_ + rg * hn);
    const float hv = (1.f - zg) * ng + zg * s_h[ln][c];
    out[(size_t)n * OUTCD + (r + 1) * NCD + c] = hv;
    hxb[(size_t)n * NCD + c] = __float2bfloat16(hv);
}

// ---------------------------------------------------------------------------
extern "C" void kernel_launch(void* const* d_in, const int* in_sizes, int n_in,
                              void* d_out, int out_size, void* d_ws, size_t ws_size,
                              hipStream_t stream) {
    const float* hx  = (const float*)d_in[0];
    const int*   ei  = (const int*)d_in[1];
    const float* ef  = (const float*)d_in[2];
    const float* fW1 = (const float*)d_in[3];
    const float* fb1 = (const float*)d_in[4];
    const float* fW2 = (const float*)d_in[5];
    const float* fb2 = (const float*)d_in[6];
    const float* Wi  = (const float*)d_in[7];
    const float* Wh  = (const float*)d_in[8];
    const float* bi  = (const float*)d_in[9];
    const float* bh  = (const float*)d_in[10];
    float* out = (float*)d_out;

    char* ws = (char*)d_ws;
    size_t off = 0;
    auto take = [&](size_t bytes) -> void* {
        void* p = ws + off;
        off = (off + bytes + 255) & ~(size_t)255;
        return p;
    };
    __hip_bfloat16* h1s = (__hip_bfloat16*)take((size_t)NEDGES * FHIDD * 2);  // 25.6 MB
    __hip_bfloat16* hxb = (__hip_bfloat16*)take((size_t)NNODES * NCD * 2);    // 1.28 MB
    __hip_bfloat16* W2f = (__hip_bfloat16*)take((size_t)NCT * 1024 * 2);      // 266 KB
    float* agg     = (float*)take((size_t)NNODES * NCD * 4);                  // 2.56 MB
    float* indeg   = (float*)take((size_t)NNODES * 4);
    int*   outcnt  = (int*)take((size_t)NNODES * 4);
    int*   csr_off = (int*)take((size_t)(NNODES + 1) * 4);
    int*   cursor  = (int*)take((size_t)NNODES * 4);
    int*   rank    = (int*)take((size_t)NEDGES * 4);
    int*   dsts    = (int*)take((size_t)NEDGES * 4);
    int*   tcnt    = (int*)take((size_t)NBLK * 4);
    int*   tile_off= (int*)take((size_t)(NBLK + 1) * 4);
    unsigned* tiles= (unsigned*)take((size_t)MAXTILES * 4);
    float* WiT     = (float*)take(3072 * 4);
    float* WhT     = (float*)take(3072 * 4);

    hipMemsetAsync(indeg,  0, (size_t)NNODES * 4, stream);
    hipMemsetAsync(outcnt, 0, (size_t)NNODES * 4, stream);
    hipMemsetAsync(cursor, 0, (size_t)NNODES * 4, stream);
    k_copy_h0<<<(NNODES * NCD) / 256, 256, 0, stream>>>(hx, out, hxb);
    k_degrees<<<(NEDGES + 255) / 256, 256, 0, stream>>>(ei, indeg, outcnt);
    k_scan<<<1, 256, 0, stream>>>(outcnt, csr_off, NNODES);
    k_fill<<<(NEDGES + 255) / 256, 256, 0, stream>>>(ei, csr_off, cursor, rank);
    k_reord<<<(NEDGES + 255) / 256, 256, 0, stream>>>(ei, rank, dsts);
    k_tcnt<<<(NBLK + 255) / 256, 256, 0, stream>>>(csr_off, tcnt);
    k_scan<<<1, 256, 0, stream>>>(tcnt, tile_off, NBLK);
    k_tfill<<<(NBLK + 255) / 256, 256, 0, stream>>>(csr_off, tile_off, tiles);
    k_h1<<<NEDGES / 4, 256, 0, stream>>>(ef, fW1, fb1, rank, h1s);
    k_w2frag<<<(NCT * 64 + 255) / 256, 256, 0, stream>>>(fW2, fb2, W2f);
    k_prep<<<12, 256, 0, stream>>>(Wi, Wh, WiT, WhT);

    for (int r = 0; r < NREPD; ++r) {
        hipMemsetAsync(agg, 0, (size_t)NNODES * NCD * 4, stream);
        k_msg<<<NBLK, 256, 0, stream>>>(tile_off, tiles, dsts, h1s, hxb, W2f, agg);
        k_gru<<<(NNODES * NCD) / 256, 256, 0, stream>>>(agg, indeg, WiT, WhT, bi, bh, out, hxb, r);
    }
}